// Round 11
// baseline (85.766 us; speedup 1.0000x reference)
//
#include <hip/hip_runtime.h>

#define NN 8
#define HH 512
#define WW 512
#define CC 3
#define KK 5
#define PADP 2
#define WROWF (WW * CC)          // 1536 floats per image row
#define NTILES 16                // row-tiles per block (one 64-px column segment)
#define NBLOCKS 2048             // 8 blocks/CU: persistent-ish streaming

typedef float f4a __attribute__((ext_vector_type(4), aligned(4)));

struct Row { f4a L0, L1, L2, L3; };   // 15-float window f0..f14 (L3 overlaps at f11)
struct Win { Row r0, r1, r2, r3, r4; };

__device__ __forceinline__ void load_row(const float* rb, Row& r) {
    r.L0 = *(const f4a*)(rb);
    r.L1 = *(const f4a*)(rb + 4);
    r.L2 = *(const f4a*)(rb + 8);
    r.L3 = *(const f4a*)(rb + 11);
}

__device__ __forceinline__ void fma_row(const Row& r, const float* wp,
                                        float& a0, float& a1, float& a2) {
    const float w0 = wp[0], w1 = wp[1], w2 = wp[2], w3 = wp[3], w4 = wp[4];
    a0 = fmaf(r.L0[0], w0, a0); a1 = fmaf(r.L0[1], w0, a1); a2 = fmaf(r.L0[2], w0, a2);
    a0 = fmaf(r.L0[3], w1, a0); a1 = fmaf(r.L1[0], w1, a1); a2 = fmaf(r.L1[1], w1, a2);
    a0 = fmaf(r.L1[2], w2, a0); a1 = fmaf(r.L1[3], w2, a1); a2 = fmaf(r.L2[0], w2, a2);
    a0 = fmaf(r.L2[1], w3, a0); a1 = fmaf(r.L2[2], w3, a1); a2 = fmaf(r.L2[3], w3, a2);
    a0 = fmaf(r.L3[1], w4, a0); a1 = fmaf(r.L3[2], w4, a1); a2 = fmaf(r.L3[3], w4, a2);
}

#define GLDS16(gp, lp) __builtin_amdgcn_global_load_lds( \
    (const __attribute__((address_space(1))) void*)(gp), \
    (__attribute__((address_space(3))) void*)(lp), 16, 0, 0)
#define GLDS4(gp, lp) __builtin_amdgcn_global_load_lds( \
    (const __attribute__((address_space(1))) void*)(gp), \
    (__attribute__((address_space(3))) void*)(lp), 4, 0, 0)

// stage one tile's 64x25 weights (6400B) into an LDS buffer: exactly 7 VMEM ops
#define STAGE(dst, row) do {                                            \
    const char* _s = (const char*)(wt + ((long)(nHH + (row)) * WW + w0) * (KK * KK)); \
    _Pragma("unroll")                                                   \
    for (int _it = 0; _it < 6; ++_it)                                   \
        GLDS16(_s + _it * 1024 + lane * 16, (dst) + _it * 256);         \
    GLDS4(_s + 6144 + lane * 4, (dst) + 1536);                          \
} while (0)

// counted wait: everything OLDER than the newest N vmem ops is complete
#define WAITK(N) do {                                                   \
    asm volatile("s_waitcnt vmcnt(" #N ")" ::: "memory");               \
    __builtin_amdgcn_sched_barrier(0);                                  \
} while (0)

// load the 5-row input window for output row `row`: exactly 20 VMEM ops
#define LOADWIN(W, row) do {                                            \
    const float* _rb = inb + (long)((row) - PADP) * WROWF + colbase;    \
    load_row(_rb + 0 * WROWF, (W).r0);                                  \
    load_row(_rb + 1 * WROWF, (W).r1);                                  \
    load_row(_rb + 2 * WROWF, (W).r2);                                  \
    load_row(_rb + 3 * WROWF, (W).r3);                                  \
    load_row(_rb + 4 * WROWF, (W).r4);                                  \
} while (0)

// interior tile: 5 register rows x 5 weight rows, store 1 output row
#define CTILE(W, WBUF, row) do {                                        \
    const float* _wp = &(WBUF)[lane * (KK * KK)];                       \
    float a0 = 0.f, a1 = 0.f, a2 = 0.f;                                 \
    fma_row((W).r0, _wp + 0,  a0, a1, a2);                              \
    fma_row((W).r1, _wp + 5,  a0, a1, a2);                              \
    fma_row((W).r2, _wp + 10, a0, a1, a2);                              \
    fma_row((W).r3, _wp + 15, a0, a1, a2);                              \
    fma_row((W).r4, _wp + 20, a0, a1, a2);                              \
    float* _o = out + ((long)(nHH + (row)) * WW + w0 + lane) * CC;      \
    _o[0] = a0; _o[1] = a1; _o[2] = a2;                                 \
} while (0)

// pipelined interior body: prefetch tile t+1 (27 ops), compute tile t
#define IBODY(CURBUF, NXTBUF, CURW, NXTW, t) do {                       \
    STAGE(NXTBUF, h0 + (t) + 1);                                        \
    LOADWIN(NXTW, h0 + (t) + 1);                                        \
    WAITK(27);                                                          \
    CTILE(CURW, CURBUF, h0 + (t));                                      \
} while (0)

// border tile: predicated scalar path, weights from LDS
#define STILE(WBUF, row) do {                                           \
    const float* _wp = &(WBUF)[lane * (KK * KK)];                       \
    const int _w = w0 + lane;                                           \
    float a0 = 0.f, a1 = 0.f, a2 = 0.f;                                 \
    _Pragma("unroll")                                                   \
    for (int dh = 0; dh < KK; ++dh) {                                   \
        const int ih = (row) + dh - PADP;                               \
        const bool rok = ((unsigned)ih < (unsigned)HH);                 \
        _Pragma("unroll")                                               \
        for (int dw = 0; dw < KK; ++dw) {                               \
            const int iw = _w + dw - PADP;                              \
            const bool ok = rok && ((unsigned)iw < (unsigned)WW);       \
            const float* p = inb + ((long)(ih * WW + iw)) * CC;         \
            float v0 = ok ? p[0] : 0.f;                                 \
            float v1 = ok ? p[1] : 0.f;                                 \
            float v2 = ok ? p[2] : 0.f;                                 \
            const float wv = _wp[dh * KK + dw];                         \
            a0 = fmaf(v0, wv, a0);                                      \
            a1 = fmaf(v1, wv, a1);                                      \
            a2 = fmaf(v2, wv, a2);                                      \
        }                                                               \
    }                                                                   \
    float* _o = out + ((long)(nHH + (row)) * WW + w0 + lane) * CC;      \
    _o[0] = a0; _o[1] = a1; _o[2] = a2;                                 \
} while (0)

#define SBODY(CURBUF, NXTBUF, t) do {                                   \
    STAGE(NXTBUF, h0 + (t) + 1);                                        \
    WAITK(7);                                                           \
    STILE(CURBUF, h0 + (t));                                            \
} while (0)

__global__ __launch_bounds__(64, 2) void conv_local_kernel(
    const float* __restrict__ in,   // (N,H,W,C)
    const float* __restrict__ wt,   // (N,H,W,25)
    float* __restrict__ out)        // (N,H,W,C)
{
    __shared__ float bufA[64 * KK * KK];   // 6.4 KB
    __shared__ float bufB[64 * KK * KK];   // 6.4 KB  -> 12.8 KB total

    const int lane = threadIdx.x;
    // bijective XCD swizzle: 2048 blocks = 8 x 256; XCD k streams image k only
    const int b    = ((blockIdx.x & 7) << 8) | (blockIdx.x >> 3);
    const int n    = b >> 8;
    const int rem  = b & 255;
    const int wseg = rem & 7;
    const int seg  = rem >> 3;         // 0..31
    const int w0   = wseg << 6;        // 0..448
    const int h0   = seg << 4;         // 0..496, block covers rows h0..h0+15
    const int nHH  = n * HH;

    const float* inb = in + (size_t)n * (HH * WW * CC);
    const int colbase = (w0 + lane - PADP) * CC;

    const bool interior = (wseg >= 1) && (wseg <= 6) && (seg >= 1) && (seg <= 30);

    // prologue: tile 0's weights + input window in flight
    STAGE(bufA, h0);

    if (interior) {
        Win WA, WB;
        LOADWIN(WA, h0);
        IBODY(bufA, bufB, WA, WB, 0);
        IBODY(bufB, bufA, WB, WA, 1);
        IBODY(bufA, bufB, WA, WB, 2);
        IBODY(bufB, bufA, WB, WA, 3);
        IBODY(bufA, bufB, WA, WB, 4);
        IBODY(bufB, bufA, WB, WA, 5);
        IBODY(bufA, bufB, WA, WB, 6);
        IBODY(bufB, bufA, WB, WA, 7);
        IBODY(bufA, bufB, WA, WB, 8);
        IBODY(bufB, bufA, WB, WA, 9);
        IBODY(bufA, bufB, WA, WB, 10);
        IBODY(bufB, bufA, WB, WA, 11);
        IBODY(bufA, bufB, WA, WB, 12);
        IBODY(bufB, bufA, WB, WA, 13);
        IBODY(bufA, bufB, WA, WB, 14);
        WAITK(0);
        CTILE(WB, bufB, h0 + 15);
    } else {
        SBODY(bufA, bufB, 0);
        SBODY(bufB, bufA, 1);
        SBODY(bufA, bufB, 2);
        SBODY(bufB, bufA, 3);
        SBODY(bufA, bufB, 4);
        SBODY(bufB, bufA, 5);
        SBODY(bufA, bufB, 6);
        SBODY(bufB, bufA, 7);
        SBODY(bufA, bufB, 8);
        SBODY(bufB, bufA, 9);
        SBODY(bufA, bufB, 10);
        SBODY(bufB, bufA, 11);
        SBODY(bufA, bufB, 12);
        SBODY(bufB, bufA, 13);
        SBODY(bufA, bufB, 14);
        WAITK(0);
        STILE(bufB, h0 + 15);
    }
}

extern "C" void kernel_launch(void* const* d_in, const int* in_sizes, int n_in,
                              void* d_out, int out_size, void* d_ws, size_t ws_size,
                              hipStream_t stream) {
    const float* in = (const float*)d_in[0];   // (8,512,512,3) f32
    const float* wt = (const float*)d_in[1];   // (8,512,512,25) f32
    float* out = (float*)d_out;                // (8,512,512,3) f32

    conv_local_kernel<<<NBLOCKS, 64, 0, stream>>>(in, wt, out);
}

// Round 12
// 56.539 us; speedup vs baseline: 1.5169x; 1.5169x over previous
//
#include <hip/hip_runtime.h>

#define NN 8
#define HH 512
#define WW 512
#define CC 3
#define KK 5
#define PADP 2
#define WROWF (WW * CC)          // 1536 floats per image row
#define NBLOCKS 4096             // (n, h-pair, half-row walk): 8 * 256 * 2

typedef float f4a __attribute__((ext_vector_type(4), aligned(4)));

struct Row { f4a L0, L1, L2, L3; };   // 15-float window f0..f14 (L3 overlaps at f11)

__device__ __forceinline__ void load_row(const float* rb, Row& r) {
    r.L0 = *(const f4a*)(rb);
    r.L1 = *(const f4a*)(rb + 4);
    r.L2 = *(const f4a*)(rb + 8);
    r.L3 = *(const f4a*)(rb + 11);
}

__device__ __forceinline__ void fma_row(const Row& r, const float* wp,
                                        float& a0, float& a1, float& a2) {
    const float w0 = wp[0], w1 = wp[1], w2 = wp[2], w3 = wp[3], w4 = wp[4];
    a0 = fmaf(r.L0[0], w0, a0); a1 = fmaf(r.L0[1], w0, a1); a2 = fmaf(r.L0[2], w0, a2);
    a0 = fmaf(r.L0[3], w1, a0); a1 = fmaf(r.L1[0], w1, a1); a2 = fmaf(r.L1[1], w1, a2);
    a0 = fmaf(r.L1[2], w2, a0); a1 = fmaf(r.L1[3], w2, a1); a2 = fmaf(r.L2[0], w2, a2);
    a0 = fmaf(r.L2[1], w3, a0); a1 = fmaf(r.L2[2], w3, a1); a2 = fmaf(r.L2[3], w3, a2);
    a0 = fmaf(r.L3[1], w4, a0); a1 = fmaf(r.L3[2], w4, a1); a2 = fmaf(r.L3[3], w4, a2);
}

#define GLDS16(gp, lp) __builtin_amdgcn_global_load_lds( \
    (const __attribute__((address_space(1))) void*)(gp), \
    (__attribute__((address_space(3))) void*)(lp), 16, 0, 0)
#define GLDS4(gp, lp) __builtin_amdgcn_global_load_lds( \
    (const __attribute__((address_space(1))) void*)(gp), \
    (__attribute__((address_space(3))) void*)(lp), 4, 0, 0)

__global__ __launch_bounds__(64, 4) void conv_local_kernel(
    const float* __restrict__ in,   // (N,H,W,C)
    const float* __restrict__ wt,   // (N,H,W,25)
    float* __restrict__ out)        // (N,H,W,C)
{
    __shared__ float wldsA[64 * KK * KK];   // 6.4 KB: row h0 weights
    __shared__ float wldsB[64 * KK * KK];   // 6.4 KB: row h0+1 weights

    const int lane = threadIdx.x;
    // bijective XCD swizzle: 4096 = 8 x 512; XCD k streams image k only
    const int b    = ((blockIdx.x & 7) << 9) | (blockIdx.x >> 3);
    const int n    = b >> 9;
    const int rem  = b & 511;
    const int hp   = rem >> 1;         // 0..255
    const int half = rem & 1;          // walks wseg half*4 .. half*4+3
    const int h0   = hp << 1;          // 0..510 (rows h0, h0+1)
    const int nHH  = n * HH;

    const float* inb  = in + (size_t)n * (HH * WW * CC);
    const bool  rowok = (hp >= 1) && (hp <= 254);   // h0-2 >= 0 && h0+4 <= 511

#pragma unroll 1
    for (int j = 0; j < 4; ++j) {
        const int  w0 = (((half << 2) | j)) << 6;   // contiguous weight walk
        const long p0 = (long)(nHH + h0) * WW + w0;
        const long p1 = p0 + WW;

        // previous step's ds_reads are complete (results consumed); belt-and-braces:
        asm volatile("s_waitcnt lgkmcnt(0)" ::: "memory");

        // ---- stage both rows' weights: 14 async GLDS ops, two contiguous streams ----
        {
            const char* s0 = (const char*)(wt + p0 * (KK * KK));
            const char* s1 = (const char*)(wt + p1 * (KK * KK));
#pragma unroll
            for (int it = 0; it < 6; ++it)
                GLDS16(s0 + it * 1024 + lane * 16, wldsA + it * 256);
            GLDS4(s0 + 6144 + lane * 4, wldsA + 1536);
#pragma unroll
            for (int it = 0; it < 6; ++it)
                GLDS16(s1 + it * 1024 + lane * 16, wldsB + it * 256);
            GLDS4(s1 + 6144 + lane * 4, wldsB + 1536);
        }

        const float* wp0 = &wldsA[lane * (KK * KK)];
        const float* wp1 = &wldsB[lane * (KK * KK)];
        const bool fast = rowok && (w0 != 0) && (w0 != WW - 64);

        if (fast) {
            // 6 input rows h0-2 .. h0+3 upfront (L2-hot; latency hides under wt drain)
            const float* rb = inb + ((long)(h0 - PADP) * WW + (w0 + lane - PADP)) * CC;
            Row R0, R1, R2, R3, R4, R5;
            load_row(rb + 0 * WROWF, R0);
            load_row(rb + 1 * WROWF, R1);
            load_row(rb + 2 * WROWF, R2);
            load_row(rb + 3 * WROWF, R3);
            load_row(rb + 4 * WROWF, R4);
            load_row(rb + 5 * WROWF, R5);
            asm volatile("s_waitcnt vmcnt(0)" ::: "memory");
            __builtin_amdgcn_sched_barrier(0);

            float a0 = 0.f, a1 = 0.f, a2 = 0.f;   // px (h0,   w)
            float c0 = 0.f, c1 = 0.f, c2 = 0.f;   // px (h0+1, w)
            fma_row(R0, wp0 + 0,  a0, a1, a2);
            fma_row(R1, wp0 + 5,  a0, a1, a2);
            fma_row(R1, wp1 + 0,  c0, c1, c2);
            fma_row(R2, wp0 + 10, a0, a1, a2);
            fma_row(R2, wp1 + 5,  c0, c1, c2);
            fma_row(R3, wp0 + 15, a0, a1, a2);
            fma_row(R3, wp1 + 10, c0, c1, c2);
            fma_row(R4, wp0 + 20, a0, a1, a2);
            fma_row(R4, wp1 + 15, c0, c1, c2);
            fma_row(R5, wp1 + 20, c0, c1, c2);

            float* o0 = out + (p0 + lane) * CC;
            o0[0] = a0; o0[1] = a1; o0[2] = a2;
            float* o1 = out + (p1 + lane) * CC;
            o1[0] = c0; o1[1] = c1; o1[2] = c2;
        } else {
            asm volatile("s_waitcnt vmcnt(0)" ::: "memory");
            __builtin_amdgcn_sched_barrier(0);
            // border step: predicated scalar path (R1-proven), weights from LDS
#pragma unroll
            for (int px = 0; px < 2; ++px) {
                const int hh = h0 + px;
                const int w  = w0 + lane;
                const float* wp = px ? wp1 : wp0;
                float a0 = 0.f, a1 = 0.f, a2 = 0.f;
#pragma unroll
                for (int dh = 0; dh < KK; ++dh) {
                    const int ih = hh + dh - PADP;
                    const bool rok = ((unsigned)ih < (unsigned)HH);
#pragma unroll
                    for (int dw = 0; dw < KK; ++dw) {
                        const int iw = w + dw - PADP;
                        const bool ok = rok && ((unsigned)iw < (unsigned)WW);
                        const float* p = inb + ((long)(ih * WW + iw)) * CC;
                        float v0 = ok ? p[0] : 0.f;
                        float v1 = ok ? p[1] : 0.f;
                        float v2 = ok ? p[2] : 0.f;
                        const float wv = wp[dh * KK + dw];
                        a0 = fmaf(v0, wv, a0);
                        a1 = fmaf(v1, wv, a1);
                        a2 = fmaf(v2, wv, a2);
                    }
                }
                float* o = out + ((long)(nHH + hh) * WW + w) * CC;
                o[0] = a0; o[1] = a1; o[2] = a2;
            }
        }
    }
}

extern "C" void kernel_launch(void* const* d_in, const int* in_sizes, int n_in,
                              void* d_out, int out_size, void* d_ws, size_t ws_size,
                              hipStream_t stream) {
    const float* in = (const float*)d_in[0];   // (8,512,512,3) f32
    const float* wt = (const float*)d_in[1];   // (8,512,512,25) f32
    float* out = (float*)d_out;                // (8,512,512,3) f32

    conv_local_kernel<<<NBLOCKS, 64, 0, stream>>>(in, wt, out);
}